// Round 2
// baseline (595.969 us; speedup 1.0000x reference)
//
#include <hip/hip_runtime.h>
#include <hip/hip_bf16.h>

#define CIN  16
#define COUT 32
#define DIN  32     // input D=H=W
#define DOUT 30     // output D=H=W

// Fused: 3D valid conv (NCDHW / OIDHW) + per-channel bias, y=tanh(y*s)*bp, sigmoid(y).
// Direct convolution, fp32 I/O (reference dtypes), fp32 accumulation.
// Block (32,8): w = tx (mask <30), h = ht*8+ty (mask <30).
// Each thread computes 4 outputs along d (register blocking: each x load feeds up to 3 FMAs).
__global__ __launch_bounds__(256) void conv3d_fused_kernel(
    const float* __restrict__ x,
    const float* __restrict__ wgt,
    const float* __restrict__ cbias,
    const float* __restrict__ scal,
    const float* __restrict__ bpar,
    float* __restrict__ out)
{
    __shared__ float sw[CIN * 27];

    const int bx = blockIdx.x;   // 0..31 : dt = bx&7 (8 d-tiles of 4), ht = bx>>3 (4 h-tiles of 8)
    const int co = blockIdx.y;   // 0..31
    const int b  = blockIdx.z;   // 0..15

    const int tid = threadIdx.y * 32 + threadIdx.x;

    // Stage this co's weights into LDS (16*27 = 432 floats).
    for (int i = tid; i < CIN * 27; i += 256) {
        sw[i] = wgt[co * (CIN * 27) + i];
    }
    __syncthreads();

    const float bias = cbias[co];
    const float s    = scal[co];
    const float bp   = bpar[co];

    const int dt = bx & 7;
    const int ht = bx >> 3;
    const int d0 = dt * 4;                 // 0,4,...,28
    const int h  = ht * 8 + threadIdx.y;   // 0..31
    const int w  = threadIdx.x;            // 0..31
    if (w >= DOUT || h >= DOUT) return;    // no further __syncthreads below

    // Row offsets for the 6 d-planes this thread touches, clamped in-bounds.
    // Clamped (wrong) values only ever feed outputs with d>=30, which are masked at store.
    int rowoff[6];
#pragma unroll
    for (int dz = 0; dz < 6; ++dz) {
        int dd = d0 + dz;
        if (dd > DIN - 1) dd = DIN - 1;
        rowoff[dz] = dd * (DIN * DIN);     // *1024
    }

    float acc[4] = {0.f, 0.f, 0.f, 0.f};

    const int xb = b * (CIN * DIN * DIN * DIN);
    for (int ci = 0; ci < CIN; ++ci) {
        const int cioff = xb + ci * (DIN * DIN * DIN);
        const float* swc = &sw[ci * 27];
#pragma unroll
        for (int kh = 0; kh < 3; ++kh) {
            const int hbase = cioff + (h + kh) * DIN + w;
#pragma unroll
            for (int kw = 0; kw < 3; ++kw) {
                float xv[6];
#pragma unroll
                for (int dz = 0; dz < 6; ++dz)
                    xv[dz] = x[hbase + kw + rowoff[dz]];
#pragma unroll
                for (int kd = 0; kd < 3; ++kd) {
                    const float wv = swc[(kd * 3 + kh) * 3 + kw];
#pragma unroll
                    for (int dd = 0; dd < 4; ++dd)
                        acc[dd] = fmaf(xv[dd + kd], wv, acc[dd]);
                }
            }
        }
    }

    // Epilogue: y = acc + bias; y = tanh(y*s)*bp; out = sigmoid(y).
    const int obase = (b * COUT + co) * (DOUT * DOUT * DOUT) + h * DOUT + w;
#pragma unroll
    for (int dd = 0; dd < 4; ++dd) {
        const int d = d0 + dd;
        if (d < DOUT) {
            float y = acc[dd] + bias;
            float t = y * s;
            // fast tanh: 1 - 2/(exp(2t)+1); saturates correctly for |t| large
            float th = 1.0f - 2.0f / (__expf(2.0f * t) + 1.0f);
            float z = th * bp;
            float r = 1.0f / (1.0f + __expf(-z));   // sigmoid
            out[obase + d * (DOUT * DOUT)] = r;
        }
    }
}

extern "C" void kernel_launch(void* const* d_in, const int* in_sizes, int n_in,
                              void* d_out, int out_size, void* d_ws, size_t ws_size,
                              hipStream_t stream) {
    const float* x     = (const float*)d_in[0];
    const float* wgt   = (const float*)d_in[1];
    const float* cbias = (const float*)d_in[2];
    const float* scal  = (const float*)d_in[3];
    const float* bpar  = (const float*)d_in[4];
    float* out = (float*)d_out;

    dim3 grid(32, COUT, 16);   // (d-tiles*h-tiles, co, b)
    dim3 block(32, 8);
    hipLaunchKernelGGL(conv3d_fused_kernel, grid, block, 0, stream,
                       x, wgt, cbias, scal, bpar, out);
}

// Round 3
// 144.695 us; speedup vs baseline: 4.1188x; 4.1188x over previous
//
#include <hip/hip_runtime.h>

#define NB    16
#define CIN   16
#define COUT  32
#define DIN   32
#define DOUT  30

typedef __attribute__((ext_vector_type(8)))  short  short8;
typedef __attribute__((ext_vector_type(16))) float  f32x16;

static __device__ __forceinline__ unsigned short f2bf_rne(float f) {
    unsigned int u = __builtin_bit_cast(unsigned int, f);
    u += 0x7fffu + ((u >> 16) & 1u);
    return (unsigned short)(u >> 16);
}
static __device__ __forceinline__ float bf2f(unsigned short s) {
    unsigned int u = ((unsigned int)s) << 16;
    return __builtin_bit_cast(float, u);
}

// Kernel 1: repack W[Cout][Cin][3][3][3] fp32 into MFMA A-fragment layout, bf16 hi/lo split.
// ws layout: hi: slice s (0..26) x lane (0..63) x 8 bf16 (16B chunks); lo at +1728 chunks.
// A-frag (32x32x16): lane l holds A[m=l&31][k=8*(l>>5)+j], m=co, k=ci.
__global__ __launch_bounds__(64) void repack_w(const float* __restrict__ wgt,
                                               short* __restrict__ ws) {
    const int s  = blockIdx.x;    // 0..26  (kd*9+kh*3+kw)
    const int l  = threadIdx.x;   // 0..63
    const int co  = l & 31;
    const int ci0 = (l >> 5) * 8;
    short8 vh, vl;
#pragma unroll
    for (int j = 0; j < 8; ++j) {
        float f = wgt[co * (CIN * 27) + (ci0 + j) * 27 + s];
        unsigned short h = f2bf_rne(f);
        vh[j] = (short)h;
        vl[j] = (short)f2bf_rne(f - bf2f(h));
    }
    ((short8*)ws)[s * 64 + l]            = vh;
    ((short8*)ws)[27 * 64 + s * 64 + l]  = vl;
}

// Main kernel: implicit-GEMM 3D conv + fused epilogue.
// Block = (htile, d, b): 4 waves, wave wy computes output row (b, :, d, h0+wy, 0..29)
// for all 32 co via 27 slices x 3 split-MFMAs (32x32x16 bf16).
__global__ __launch_bounds__(256) void conv3d_mfma(
    const float* __restrict__ x,
    const short* __restrict__ wsA,
    const float* __restrict__ cbias,
    const float* __restrict__ scal,
    const float* __restrict__ bpar,
    float* __restrict__ out)
{
    // staged x, bf16 split: [plane hi/lo][dz 3][row 6][w 32][ci 16] shorts = 36 KB
    __shared__ short sx[2 * 9216];
    __shared__ float sp[96];

    const int htile = blockIdx.x;   // 0..7
    const int d     = blockIdx.y;   // 0..29
    const int b     = blockIdx.z;   // 0..15

    const int tid  = threadIdx.x;
    const int wy   = tid >> 6;
    const int lane = tid & 63;

    if (tid < 32) {
        sp[tid]      = cbias[tid];
        sp[32 + tid] = scal[tid];
        sp[64 + tid] = bpar[tid];
    }

    const int h0 = htile * 4;

    // ---- stage x rows h0..h0+5, d..d+2, all 16 ci, into LDS (hi/lo bf16) ----
    // chunk c = ((dz*6+row)*32 + w)*2 + hi8 ; each chunk = 8 ci values (16B), LDS-contiguous.
    const int xb = b * (CIN * DIN * DIN * DIN);
    for (int c = tid; c < 1152; c += 256) {
        const int hi8 = c & 1;
        const int r2  = c >> 1;
        const int w   = r2 & 31;
        const int rr  = r2 >> 5;        // dz*6+row, 0..17
        const int dz  = rr / 6;
        const int row = rr - dz * 6;
        int h_in = h0 + row; if (h_in > 31) h_in = 31;   // htile 7 halo clamp (garbage rows unused)
        const int gbase = xb + (hi8 * 8) * (DIN * DIN * DIN)
                        + (d + dz) * (DIN * DIN) + h_in * DIN + w;
        short8 vh, vl;
#pragma unroll
        for (int j = 0; j < 8; ++j) {
            float f = x[gbase + j * (DIN * DIN * DIN)];
            unsigned short h = f2bf_rne(f);
            vh[j] = (short)h;
            vl[j] = (short)f2bf_rne(f - bf2f(h));
        }
        *(short8*)(sx + c * 8)        = vh;
        *(short8*)(sx + 9216 + c * 8) = vl;
    }
    __syncthreads();

    const int h = h0 + wy;
    if (h >= DOUT) return;    // only barrier above; safe to exit

    const int n  = lane & 31;   // output w (30 valid + 2 pad)
    const int hi = lane >> 5;

    // per-lane LDS offsets (shorts) within a [w][ci] row, for kw = 0..2 (clamped for pad lanes)
    int wofs[3];
#pragma unroll
    for (int kw = 0; kw < 3; ++kw) {
        int wc = n + kw; if (wc > 31) wc = 31;
        wofs[kw] = wc * 16 + hi * 8;
    }

    f32x16 acc;
#pragma unroll
    for (int i = 0; i < 16; ++i) acc[i] = 0.0f;

    const short8* wa = (const short8*)wsA;
#pragma unroll
    for (int kd = 0; kd < 3; ++kd) {
#pragma unroll
        for (int kh = 0; kh < 3; ++kh) {
            const int rbase = (kd * 6 + wy + kh) * (32 * 16);
#pragma unroll
            for (int kw = 0; kw < 3; ++kw) {
                const int s = kd * 9 + kh * 3 + kw;
                short8 ah = wa[s * 64 + lane];
                short8 al = wa[1728 + s * 64 + lane];
                short8 bh = *(const short8*)(sx + rbase + wofs[kw]);
                short8 bl = *(const short8*)(sx + 9216 + rbase + wofs[kw]);
                acc = __builtin_amdgcn_mfma_f32_32x32x16_bf16(ah, bh, acc, 0, 0, 0);
                acc = __builtin_amdgcn_mfma_f32_32x32x16_bf16(ah, bl, acc, 0, 0, 0);
                acc = __builtin_amdgcn_mfma_f32_32x32x16_bf16(al, bh, acc, 0, 0, 0);
            }
        }
    }

    // ---- epilogue: bias, tanh*scale, *bp, sigmoid; C/D map: co=(r&3)+8*(r>>2)+4*hi, col=n ----
    if (n < DOUT) {
        const int obase = b * (COUT * DOUT * DOUT * DOUT)
                        + d * (DOUT * DOUT) + h * DOUT + n;
#pragma unroll
        for (int r = 0; r < 16; ++r) {
            const int co = (r & 3) + 8 * (r >> 2) + 4 * hi;
            float y  = acc[r] + sp[co];
            float t  = y * sp[32 + co];
            float th = 1.0f - 2.0f / (__expf(2.0f * t) + 1.0f);
            float z  = th * sp[64 + co];
            float rr = 1.0f / (1.0f + __expf(-z));
            out[obase + co * (DOUT * DOUT * DOUT)] = rr;
        }
    }
}

extern "C" void kernel_launch(void* const* d_in, const int* in_sizes, int n_in,
                              void* d_out, int out_size, void* d_ws, size_t ws_size,
                              hipStream_t stream) {
    const float* x     = (const float*)d_in[0];
    const float* wgt   = (const float*)d_in[1];
    const float* cbias = (const float*)d_in[2];
    const float* scal  = (const float*)d_in[3];
    const float* bpar  = (const float*)d_in[4];
    float* out = (float*)d_out;
    short* ws  = (short*)d_ws;   // 27*64*16B * 2 = 55296 bytes used

    hipLaunchKernelGGL(repack_w, dim3(27), dim3(64), 0, stream, wgt, ws);
    hipLaunchKernelGGL(conv3d_mfma, dim3(8, DOUT, NB), dim3(256), 0, stream,
                       x, ws, cbias, scal, bpar, out);
}